// Round 2
// baseline (390.016 us; speedup 1.0000x reference)
//
#include <hip/hip_runtime.h>
#include <math.h>

constexpr int M   = 64;       // rows of phi / Y
constexpr int NR  = 256;      // rows of X
constexpr int KK  = NR + M;   // 320: stacked K dim  [W | Z] · [X ; Y]
constexpr int NC  = 131072;   // columns
constexpr int BN  = 64;       // columns per block-tile
constexpr int NTILE = NC / BN;   // 2048
constexpr int GRID  = 512;       // blocks; block b owns tiles b, b+512, b+1024, b+1536
constexpr int TPB   = NTILE / GRID;  // 4 tiles per block
constexpr float THR = 0.1f;

typedef __bf16 bf16x8 __attribute__((ext_vector_type(8)));
typedef float  f32x4  __attribute__((ext_vector_type(4)));

static __device__ __forceinline__ unsigned short f2bf(float f) {
    unsigned int u = __float_as_uint(f);
    u += 0x7FFFu + ((u >> 16) & 1u);        // round-to-nearest-even
    return (unsigned short)(u >> 16);
}

// A stored fragment-linear: chunk ((wave*10 + kb)*4 + mt) of 512 bf16 (1 KiB);
// element (lane*8 + j) within chunk, lane = quad*16 + nlo.
// Fragment element (lane, j) <-> A(i = wave*64 + mt*16 + nlo, kk = kb*32 + quad*8 + j)
static __device__ __forceinline__ int a_off(int i, int kk) {
    const int wave = i >> 6, mt = (i >> 4) & 3, nlo = i & 15;
    const int kb = kk >> 5, quad = (kk >> 3) & 3, j = kk & 7;
    return (((wave * 10 + kb) * 4 + mt) << 9) + ((quad * 16 + nlo) << 3) + j;
}

__global__ __launch_bounds__(256)
void k_copy_phi(const float* __restrict__ phi, float* __restrict__ out)
{
    int i = blockIdx.x * 256 + threadIdx.x;
    out[i] = phi[i];
}

// Build A = [ I - s*phi^T*phi  |  s*phi^T ]  (256 x 320, bf16) in ws,
// stored in MFMA-fragment-linear order (a_off). Block i computes row i.
__global__ __launch_bounds__(256)
void k_prep(const float* __restrict__ phi, const float* __restrict__ step,
            unsigned short* __restrict__ A)
{
    __shared__ float ph[M * NR];            // 64 KiB, phi row-major 64x256
    const int i = blockIdx.x, j = threadIdx.x;
    for (int t = j; t < M * NR; t += 256) ph[t] = phi[t];
    __syncthreads();
    const float s = step[0];
    float d = 0.f;
    #pragma unroll
    for (int m = 0; m < M; ++m)
        d = fmaf(ph[m * NR + i], ph[m * NR + j], d);
    float w = ((i == j) ? 1.f : 0.f) - s * d;
    A[a_off(i, j)] = f2bf(w);
    if (j < M) A[a_off(i, NR + j)] = f2bf(s * ph[j * NR + i]);
}

// U = A[256x320] * [X;Y][320xN], threshold, copy for cols >= k.
// Pipelined multi-tile version: block b owns tiles {b + i*GRID}, i=0..3.
// Gemm tiles form a prefix of that list (tile index increases with i), so the
// steady-state loop is: convert v->LDS ; bar ; issue burst for next gemm tile ;
// MFMA (LDS + A) ; bar ; epilogue store. The next tile's 80 KB of global loads
// are in flight under the ~1800-cycle MFMA+store phase -> continuous HBM stream.
// LDS B: bf16, zero-pad, XOR-swizzled:
//   byte(kb,n,kl) = kb*4096 + n*64 + kl*2, then ^ ((n>>1)&7)<<4
//   -> ds_read_b128 fragment reads bank-uniform, staging ds_write_b32 4-way.
__global__ __launch_bounds__(256, 2)
void k_gemm(const unsigned short* __restrict__ A,
            const float* __restrict__ X,
            const float* __restrict__ Y,
            const int*   __restrict__ idxp,
            float* __restrict__ outX)
{
    const int k   = idxp[0] + 1;
    const int tid = threadIdx.x;
    const int c4 = tid & 15, rg = tid >> 4;
    const int lane = tid & 63, wave = tid >> 6;
    const int quad = lane >> 4, nlo = lane & 15;
    const int mbase = wave * 64;

    __shared__ unsigned int Bu32[10 * 4096 / 4];   // 40960 B

    f32x4 v0[10], v1[10];                    // in-flight tile (80 VGPRs)

    auto burst = [&](int n0) {               // issue whole-tile loads back-to-back
        #pragma unroll
        for (int it = 0; it < 10; ++it) {
            const int r0 = 32 * it + 2 * rg; // even row; pair never crosses X/Y seam
            const float *s0, *s1;
            if (r0 < NR) { s0 = X + (size_t)r0 * NC;        s1 = X + (size_t)(r0 + 1) * NC; }
            else         { s0 = Y + (size_t)(r0 - NR) * NC; s1 = Y + (size_t)(r0 + 1 - NR) * NC; }
            v0[it] = *(const f32x4*)(s0 + n0 + 4 * c4);
            v1[it] = *(const f32x4*)(s1 + n0 + 4 * c4);
        }
    };

    const unsigned short* Abase = A + ((wave * 40) << 9) + (lane << 3);
    // swz for reads: n = nlo + nt*16 -> ((n>>1)&7)<<4 == ((nlo>>1)&7)<<4 (nt-independent)
    const char* Bbase = (const char*)Bu32 +
                        (((unsigned)(nlo * 64 + quad * 16)) ^ ((nlo & 14) << 3));

    // prologue: preload first tile if it's a gemm tile
    if (blockIdx.x * BN < k) burst(blockIdx.x * BN);

    #pragma unroll
    for (int i = 0; i < TPB; ++i) {
        const int n0 = (blockIdx.x + i * GRID) * BN;

        if (n0 >= k) {                       // pure-copy tile (no LDS, no barriers)
            #pragma unroll
            for (int r = rg; r < NR; r += 16) {
                const float4* src = (const float4*)(X + (size_t)r * NC + n0);
                float4*       dst = (float4*)(outX + (size_t)r * NC + n0);
                dst[c4] = src[c4];
            }
            continue;
        }

        // ---- A kb=0 prefetch (L2) hides under the convert VALU phase ----
        bf16x8 a_cur[4], a_nxt[4];
        #pragma unroll
        for (int mt = 0; mt < 4; ++mt)
            a_cur[mt] = *(const bf16x8*)(Abase + (mt << 9));

        // ---- convert staged regs -> swizzled bf16 LDS ----
        #pragma unroll
        for (int it = 0; it < 10; ++it) {
            const int kl2 = 4 * rg;          // kl*2 bytes, kl = 2*rg
            #pragma unroll
            for (int c = 0; c < 4; ++c) {
                const int n = 4 * c4 + c;
                const int byteoff = (it * 4096 + n * 64 + kl2) ^ ((n & 14) << 3);
                Bu32[byteoff >> 2] =
                    (unsigned int)f2bf(v0[it][c]) | ((unsigned int)f2bf(v1[it][c]) << 16);
            }
        }
        __syncthreads();

        // ---- issue next gemm tile's burst; lands during MFMA+epilogue ----
        {
            const int n0n = n0 + GRID * BN;
            if ((i + 1 < TPB) && (n0n < k)) burst(n0n);
        }

        // ---- MFMA loop ----
        f32x4 acc[4][4];
        #pragma unroll
        for (int mt = 0; mt < 4; ++mt)
            #pragma unroll
            for (int nt = 0; nt < 4; ++nt)
                acc[mt][nt] = (f32x4){0.f, 0.f, 0.f, 0.f};

        #pragma unroll
        for (int kb = 0; kb < 10; ++kb) {
            if (kb < 9) {                    // 1-deep A prefetch across kb
                #pragma unroll
                for (int mt = 0; mt < 4; ++mt)
                    a_nxt[mt] = *(const bf16x8*)(Abase + (((kb + 1) * 4 + mt) << 9));
            }
            bf16x8 bfr[4];
            #pragma unroll
            for (int nt = 0; nt < 4; ++nt)
                bfr[nt] = *(const bf16x8*)(Bbase + kb * 4096 + nt * 1024);
            #pragma unroll
            for (int mt = 0; mt < 4; ++mt)
                #pragma unroll
                for (int nt = 0; nt < 4; ++nt)
                    acc[mt][nt] = __builtin_amdgcn_mfma_f32_16x16x32_bf16(
                        a_cur[mt], bfr[nt], acc[mt][nt], 0, 0, 0);
            #pragma unroll
            for (int mt = 0; mt < 4; ++mt) a_cur[mt] = a_nxt[mt];
        }
        __syncthreads();                     // LDS reads done before next tile's writes

        // ---- epilogue: threshold + boundary copy + store ----
        const bool boundary = (n0 + BN > k);
        #pragma unroll
        for (int mt = 0; mt < 4; ++mt) {
            #pragma unroll
            for (int nt = 0; nt < 4; ++nt) {
                const int col = n0 + nt * 16 + nlo;
                #pragma unroll
                for (int reg = 0; reg < 4; ++reg) {
                    const int row = mbase + mt * 16 + quad * 4 + reg;
                    float v = acc[mt][nt][reg];
                    v = (fabsf(v) > THR) ? v : 0.f;
                    if (boundary && col >= k) v = X[(size_t)row * NC + col];
                    outX[(size_t)row * NC + col] = v;
                }
            }
        }
    }
}

extern "C" void kernel_launch(void* const* d_in, const int* in_sizes, int n_in,
                              void* d_out, int out_size, void* d_ws, size_t ws_size,
                              hipStream_t stream)
{
    const float* phi  = (const float*)d_in[0];
    const float* X    = (const float*)d_in[1];
    const float* Y    = (const float*)d_in[2];
    const float* step = (const float*)d_in[3];
    const int*   idx  = (const int*)d_in[4];
    float* out = (float*)d_out;
    unsigned short* A = (unsigned short*)d_ws;   // 256*320*2 = 160 KiB, fragment-linear

    k_copy_phi<<<(M * NR) / 256, 256, 0, stream>>>(phi, out);
    k_prep<<<NR, 256, 0, stream>>>(phi, step, A);
    k_gemm<<<GRID, 256, 0, stream>>>(A, X, Y, idx, out + M * NR);
}

// Round 3
// 357.917 us; speedup vs baseline: 1.0897x; 1.0897x over previous
//
#include <hip/hip_runtime.h>
#include <math.h>

constexpr int M   = 64;       // rows of phi / Y
constexpr int NR  = 256;      // rows of X
constexpr int KK  = NR + M;   // 320: stacked K dim  [W | Z] · [X ; Y]
constexpr int NC  = 131072;   // columns
constexpr int BN  = 64;       // columns per block-tile
constexpr int NTILE = NC / BN;      // 2048
constexpr int GRID  = 512;          // 2 blocks/CU exactly
constexpr int TPB   = NTILE / GRID; // 4 tiles per block
constexpr float THR = 0.1f;

typedef __bf16 bf16x8 __attribute__((ext_vector_type(8)));
typedef float  f32x4  __attribute__((ext_vector_type(4)));
typedef unsigned int u32;

static __device__ __forceinline__ unsigned short f2bf(float f) {
    unsigned int u = __float_as_uint(f);
    u += 0x7FFFu + ((u >> 16) & 1u);        // round-to-nearest-even
    return (unsigned short)(u >> 16);
}

// async global->LDS DMA, 16 B per lane; LDS dest is wave-uniform base + lane*16
static __device__ __forceinline__ void gload_lds16(const void* g, void* l) {
    __builtin_amdgcn_global_load_lds(
        (const __attribute__((address_space(1))) u32*)g,
        (__attribute__((address_space(3))) u32*)l, 16, 0, 0);
}

template<int N> static __device__ __forceinline__ void waitv() {
    asm volatile("s_waitcnt vmcnt(%0)" :: "i"(N) : "memory");
    __builtin_amdgcn_sched_barrier(0);
}
static __device__ __forceinline__ void waitl0() {
    asm volatile("s_waitcnt lgkmcnt(0)" ::: "memory");
    __builtin_amdgcn_sched_barrier(0);
}
// raw barrier: does NOT drain vmcnt (unlike __syncthreads) -> ring stays in flight.
// asm fences stop the compiler moving LDS ops across it.
static __device__ __forceinline__ void barrier_raw() {
    asm volatile("" ::: "memory");
    __builtin_amdgcn_s_barrier();
    asm volatile("" ::: "memory");
}

// A stored fragment-linear: chunk ((wave*10 + kb)*4 + mt) of 512 bf16 (1 KiB);
// element (lane*8 + j); lane = quad*16 + nlo.
// (i = wave*64 + mt*16 + nlo, kk = kb*32 + quad*8 + j)
static __device__ __forceinline__ int a_off(int i, int kk) {
    const int wave = i >> 6, mt = (i >> 4) & 3, nlo = i & 15;
    const int kb = kk >> 5, quad = (kk >> 3) & 3, j = kk & 7;
    return (((wave * 10 + kb) * 4 + mt) << 9) + ((quad * 16 + nlo) << 3) + j;
}

__global__ __launch_bounds__(256)
void k_copy_phi(const float* __restrict__ phi, float* __restrict__ out)
{
    int i = blockIdx.x * 256 + threadIdx.x;
    out[i] = phi[i];
}

// Build A = [ I - s*phi^T*phi  |  s*phi^T ]  (256 x 320, bf16) in ws,
// stored fragment-linear (a_off). Block i computes row i.
__global__ __launch_bounds__(256)
void k_prep(const float* __restrict__ phi, const float* __restrict__ step,
            unsigned short* __restrict__ A)
{
    __shared__ float ph[M * NR];            // 64 KiB, phi row-major 64x256
    const int i = blockIdx.x, j = threadIdx.x;
    for (int t = j; t < M * NR; t += 256) ph[t] = phi[t];
    __syncthreads();
    const float s = step[0];
    float d = 0.f;
    #pragma unroll
    for (int m = 0; m < M; ++m)
        d = fmaf(ph[m * NR + i], ph[m * NR + j], d);
    float w = ((i == j) ? 1.f : 0.f) - s * d;
    A[a_off(i, j)] = f2bf(w);
    if (j < M) A[a_off(i, NR + j)] = f2bf(s * ph[j * NR + i]);
}

// U = A[256x320] * [X;Y][320xN], threshold, copy for cols >= k.
// Ring-pipelined: 4-slot f32 LDS ring (8 KB = one 32-row kb-block per slot),
// filled by global_load_lds (async DMA, no VGPR cost). Per wave, per kb:
//   waitv(6) [slot landed] -> ds_read f32 -> f2bf pack -> ds_write swizzled bf16
//   -> lgkmcnt(0) -> issue DMA for slot+4 (overwrites just-read slot).
// A lives entirely in registers (loaded once) so the MFMA loop has zero vmem
// and the vmcnt ring contract stays exact. Raw s_barrier (no vmcnt drain)
// around the bf16 tile handoff. Loads stay ~3 slots (24 KB/block) in flight
// continuously -> HBM-paced, not latency-paced.
__global__ __launch_bounds__(256, 2)
void k_gemm(const unsigned short* __restrict__ A,
            const float* __restrict__ X,
            const float* __restrict__ Y,
            const int*   __restrict__ idxp,
            float* __restrict__ outX)
{
    const int k   = idxp[0] + 1;
    const int tid = threadIdx.x;
    const int lane = tid & 63, wave = tid >> 6;
    const int quad = lane >> 4, nlo = lane & 15;
    const int c4 = tid & 15, rg = tid >> 4;

    __shared__ __align__(16) unsigned char lds_raw[73728];
    u32*   Bu32 = (u32*)lds_raw;               // 40960 B bf16 tile (swizzled)
    char*  ring = (char*)(lds_raw + 40960);    // 32768 B f32 ring: 4 slots x 8192

    // gemm tiles form a prefix of this block's tile list (n0 increases with i)
    int n_gemm = 0;
    #pragma unroll
    for (int i = 0; i < TPB; ++i)
        if ((blockIdx.x + i * GRID) * BN < k) ++n_gemm;
    const int gtotal = n_gemm * 10;            // total kb-blocks to stage

    // ---- A fragments -> registers, once per block (160 VGPR) ----
    bf16x8 af[10][4];
    {
        const unsigned short* Ab = A + ((wave * 40) << 9) + (lane << 3);
        #pragma unroll
        for (int kb = 0; kb < 10; ++kb)
            #pragma unroll
            for (int mt = 0; mt < 4; ++mt)
                af[kb][mt] = *(const bf16x8*)(Ab + (((kb << 2) + mt) << 9));
    }

    // ---- stage-issue state (wave-uniform) ----
    int s_n0 = blockIdx.x * BN;                // n0 of next slot's tile
    int s_kb = 0;
    int gi   = 0;                              // slots issued
    auto issue = [&]() {
        const int slot = gi & 3;
        const int kbase = s_kb * 32;
        #pragma unroll
        for (int q = 0; q < 2; ++q) {
            const int r = kbase + 8 * wave + 4 * q + (lane >> 4);
            const float* src = (r < NR ? X + (size_t)r * NC
                                       : Y + (size_t)(r - NR) * NC)
                               + s_n0 + (lane & 15) * 4;
            gload_lds16(src, ring + slot * 8192 + wave * 2048 + q * 1024);
        }
        ++gi; ++s_kb;
        if (s_kb == 10) { s_kb = 0; s_n0 += GRID * BN; }
    };

    // prologue: fill the ring (gtotal >= 10 for every block at this k)
    issue(); issue(); issue(); issue();

    const char* Bbase = (const char*)Bu32 +
                        (((unsigned)(nlo * 64 + quad * 16)) ^ ((nlo & 14) << 3));
    const int rp  = lane >> 4;                 // 0..3: row-pair within wave's 8 rows
    const int n4  = (lane & 15) * 4;           // 4 cols per lane
    const int klw = 8 * wave + 2 * rp;         // even kl of the pair
    const int mbase = wave * 64;

    for (int i = 0; i < n_gemm; ++i) {
        const int n0 = (blockIdx.x + i * GRID) * BN;
        const bool last = (i == n_gemm - 1);

        // ---- convert phase: ring f32 -> swizzled bf16 tile ----
        #pragma unroll
        for (int kb = 0; kb < 10; ++kb) {
            if (last) {                        // tail: fewer slots in flight
                if      (kb <= 6) waitv<6>();
                else if (kb == 7) waitv<4>();
                else if (kb == 8) waitv<2>();
                else              waitv<0>();
            } else {
                waitv<6>();                    // oldest slot landed (2 instrs/slot/wave)
            }
            const int slot = (i * 10 + kb) & 3;
            const char* f0 = ring + slot * 8192 + klw * 256 + n4 * 4;
            f32x4 r0 = *(const f32x4*)f0;
            f32x4 r1 = *(const f32x4*)(f0 + 256);   // odd row of the pair
            #pragma unroll
            for (int c = 0; c < 4; ++c) {
                const int n = n4 + c;
                const int byteoff = (kb * 4096 + n * 64 + klw * 2) ^ ((n & 14) << 3);
                *(u32*)((char*)Bu32 + byteoff) =
                    (u32)f2bf(r0[c]) | ((u32)f2bf(r1[c]) << 16);
            }
            waitl0();                          // my slot reads + bf16 writes complete
            if (gi < gtotal) issue();          // DMA next kb-block into freed slot
        }
        barrier_raw();                         // bf16 tile ready (lgkm0 done per-wave)

        // ---- MFMA phase (zero vmem: A in regs, B via conflict-free b128) ----
        f32x4 acc[4][4];
        #pragma unroll
        for (int mt = 0; mt < 4; ++mt)
            #pragma unroll
            for (int nt = 0; nt < 4; ++nt)
                acc[mt][nt] = (f32x4){0.f, 0.f, 0.f, 0.f};

        #pragma unroll
        for (int kb = 0; kb < 10; ++kb) {
            bf16x8 bfr[4];
            #pragma unroll
            for (int nt = 0; nt < 4; ++nt)
                bfr[nt] = *(const bf16x8*)(Bbase + kb * 4096 + nt * 1024);
            #pragma unroll
            for (int mt = 0; mt < 4; ++mt)
                #pragma unroll
                for (int nt = 0; nt < 4; ++nt)
                    acc[mt][nt] = __builtin_amdgcn_mfma_f32_16x16x32_bf16(
                        af[kb][mt], bfr[nt], acc[mt][nt], 0, 0, 0);
        }

        // ---- epilogue: threshold + boundary copy + store ----
        const bool boundary = (n0 + BN > k);
        #pragma unroll
        for (int mt = 0; mt < 4; ++mt) {
            #pragma unroll
            for (int nt = 0; nt < 4; ++nt) {
                const int col = n0 + nt * 16 + nlo;
                #pragma unroll
                for (int reg = 0; reg < 4; ++reg) {
                    const int row = mbase + mt * 16 + quad * 4 + reg;
                    float v = acc[mt][nt][reg];
                    v = (fabsf(v) > THR) ? v : 0.f;
                    if (boundary && col >= k) v = X[(size_t)row * NC + col];
                    outX[(size_t)row * NC + col] = v;
                }
            }
        }
        barrier_raw();                         // frag reads consumed before next converts
    }

    // ---- pure-copy tiles (suffix; no barriers, no ring) ----
    for (int i = n_gemm; i < TPB; ++i) {
        const int n0 = (blockIdx.x + i * GRID) * BN;
        #pragma unroll
        for (int r = rg; r < NR; r += 16) {
            const float4* src = (const float4*)(X + (size_t)r * NC + n0);
            float4*       dst = (float4*)(outX + (size_t)r * NC + n0);
            dst[c4] = src[c4];
        }
    }
}

extern "C" void kernel_launch(void* const* d_in, const int* in_sizes, int n_in,
                              void* d_out, int out_size, void* d_ws, size_t ws_size,
                              hipStream_t stream)
{
    const float* phi  = (const float*)d_in[0];
    const float* X    = (const float*)d_in[1];
    const float* Y    = (const float*)d_in[2];
    const float* step = (const float*)d_in[3];
    const int*   idx  = (const int*)d_in[4];
    float* out = (float*)d_out;
    unsigned short* A = (unsigned short*)d_ws;   // 256*320*2 = 160 KiB, fragment-linear

    k_copy_phi<<<(M * NR) / 256, 256, 0, stream>>>(phi, out);
    k_prep<<<NR, 256, 0, stream>>>(phi, step, A);
    k_gemm<<<GRID, 256, 0, stream>>>(A, X, Y, idx, out + M * NR);
}

// Round 5
// 307.672 us; speedup vs baseline: 1.2676x; 1.1633x over previous
//
#include <hip/hip_runtime.h>
#include <math.h>

constexpr int M   = 64;       // rows of phi / Y
constexpr int NR  = 256;      // rows of X
constexpr int KK  = NR + M;   // 320: stacked K dim  [W | Z] · [X ; Y]
constexpr int NC  = 131072;   // columns
constexpr int BN  = 32;       // columns per block (was 64; more blocks/CU now)
constexpr float THR = 0.1f;

typedef __bf16 bf16x8 __attribute__((ext_vector_type(8)));
typedef float  f32x4  __attribute__((ext_vector_type(4)));
typedef unsigned int u32;

static __device__ __forceinline__ unsigned short f2bf(float f) {
    unsigned int u = __float_as_uint(f);
    u += 0x7FFFu + ((u >> 16) & 1u);        // round-to-nearest-even
    return (unsigned short)(u >> 16);
}

// A stored fragment-linear: chunk ((wave*10 + kb)*4 + mt) of 512 bf16 (1 KiB);
// element (lane*8 + j); lane = quad*16 + nlo.
// (i = wave*64 + mt*16 + nlo, kk = kb*32 + quad*8 + j)
static __device__ __forceinline__ int a_off(int i, int kk) {
    const int wave = i >> 6, mt = (i >> 4) & 3, nlo = i & 15;
    const int kb = kk >> 5, quad = (kk >> 3) & 3, j = kk & 7;
    return (((wave * 10 + kb) * 4 + mt) << 9) + ((quad * 16 + nlo) << 3) + j;
}

__global__ __launch_bounds__(256)
void k_copy_phi(const float* __restrict__ phi, float* __restrict__ out)
{
    int i = blockIdx.x * 256 + threadIdx.x;
    out[i] = phi[i];
}

// Build A = [ I - s*phi^T*phi  |  s*phi^T ]  (256 x 320, bf16) in ws,
// stored fragment-linear (a_off). Block i computes row i.
__global__ __launch_bounds__(256)
void k_prep(const float* __restrict__ phi, const float* __restrict__ step,
            unsigned short* __restrict__ A)
{
    __shared__ float ph[M * NR];            // 64 KiB, phi row-major 64x256
    const int i = blockIdx.x, j = threadIdx.x;
    for (int t = j; t < M * NR; t += 256) ph[t] = phi[t];
    __syncthreads();
    const float s = step[0];
    float d = 0.f;
    #pragma unroll
    for (int m = 0; m < M; ++m)
        d = fmaf(ph[m * NR + i], ph[m * NR + j], d);
    float w = ((i == j) ? 1.f : 0.f) - s * d;
    A[a_off(i, j)] = f2bf(w);
    if (j < M) A[a_off(i, NR + j)] = f2bf(s * ph[j * NR + i]);
}

// U = A[256x320] * [X;Y][320xN], threshold, copy for cols >= k.
// BN=32 tiles: LDS 20480 B -> more blocks/CU resident. Staggered independent
// blocks cover each other's latency-exposed phases (occupancy replaces
// pipelining as the latency-hiding mechanism; R2/R3 proved register-based
// pipelining spills at the 128-VGPR compiler cap).
// Thread map: c8 = tid&7 (4-col group), rp = (tid>>3)&15 (row pair),
// kh = tid>>7 (kb parity); it=0..4 -> kb = 2*it+kh. 10 x 16B loads/thread.
// LDS B: bf16, XOR-swizzled: byte(kb,n,kl) = kb*2048 + n*64 + kl*2,
// then ^ ((n&14)<<3) -> b128 fragment reads <=2-way (free), staging
// ds_write_b32 exactly 2-way (free).
__global__ __launch_bounds__(256, 4)
void k_gemm(const unsigned short* __restrict__ A,
            const float* __restrict__ X,
            const float* __restrict__ Y,
            const int*   __restrict__ idxp,
            float* __restrict__ outX)
{
    const int k   = idxp[0] + 1;
    const int n0  = blockIdx.x * BN;
    const int tid = threadIdx.x;

    if (n0 >= k) {                           // pure-copy fast path
        const int c8 = tid & 7, rg = tid >> 3;
        #pragma unroll
        for (int r = rg; r < NR; r += 32) {
            const float4* src = (const float4*)(X + (size_t)r * NC + n0);
            float4*       dst = (float4*)(outX + (size_t)r * NC + n0);
            dst[c8] = src[c8];
        }
        return;
    }

    __shared__ u32 Bu32[10 * 2048 / 4];      // 20480 B

    const int c8 = tid & 7, rp = (tid >> 3) & 15, kh = tid >> 7;
    const int lane = tid & 63, wave = tid >> 6;
    const int quad = lane >> 4, nlo = lane & 15;

    // ---- burst-load the whole [X;Y] tile into registers (10 float4) ----
    f32x4 v0[5], v1[5];
    #pragma unroll
    for (int it = 0; it < 5; ++it) {
        const int kb = 2 * it + kh;
        const int r0 = kb * 32 + 2 * rp;     // even row; pair never crosses X/Y seam
        const float *s0, *s1;
        if (r0 < NR) { s0 = X + (size_t)r0 * NC;        s1 = X + (size_t)(r0 + 1) * NC; }
        else         { s0 = Y + (size_t)(r0 - NR) * NC; s1 = Y + (size_t)(r0 + 1 - NR) * NC; }
        v0[it] = *(const f32x4*)(s0 + n0 + 4 * c8);
        v1[it] = *(const f32x4*)(s1 + n0 + 4 * c8);
    }

    // ---- prefetch A fragments for kb=0 (coalesced 1KB/wave chunks, L2-hot) ----
    const unsigned short* Abase = A + ((wave * 40) << 9) + (lane << 3);
    bf16x8 a_cur[4], a_nxt[4];
    #pragma unroll
    for (int mt = 0; mt < 4; ++mt)
        a_cur[mt] = *(const bf16x8*)(Abase + (mt << 9));

    // ---- convert + write swizzled LDS ----
    #pragma unroll
    for (int it = 0; it < 5; ++it) {
        const int kb  = 2 * it + kh;
        const int kl2 = 4 * rp;              // byte offset of row 2*rp (kl*2)
        #pragma unroll
        for (int c = 0; c < 4; ++c) {
            const int n = 4 * c8 + c;
            const int byteoff = (kb * 2048 + n * 64 + kl2) ^ ((n & 14) << 3);
            Bu32[byteoff >> 2] =
                (u32)f2bf(v0[it][c]) | ((u32)f2bf(v1[it][c]) << 16);
        }
    }
    __syncthreads();

    f32x4 acc[4][2];
    #pragma unroll
    for (int mt = 0; mt < 4; ++mt)
        #pragma unroll
        for (int nt = 0; nt < 2; ++nt)
            acc[mt][nt] = (f32x4){0.f, 0.f, 0.f, 0.f};

    // swz for reads: n = nlo + nt*16 -> ((n>>1)&7)<<4 == ((nlo>>1)&7)<<4 (nt-independent)
    const char* Bbase = (const char*)Bu32 +
                        (((unsigned)(nlo * 64 + quad * 16)) ^ ((nlo & 14) << 3));

    #pragma unroll
    for (int kb = 0; kb < 10; ++kb) {
        if (kb < 9) {                        // 1-deep A prefetch across kb
            #pragma unroll
            for (int mt = 0; mt < 4; ++mt)
                a_nxt[mt] = *(const bf16x8*)(Abase + (((kb + 1) * 4 + mt) << 9));
        }
        bf16x8 bfr[2];
        #pragma unroll
        for (int nt = 0; nt < 2; ++nt)
            bfr[nt] = *(const bf16x8*)(Bbase + kb * 2048 + nt * 1024);
        #pragma unroll
        for (int mt = 0; mt < 4; ++mt)
            #pragma unroll
            for (int nt = 0; nt < 2; ++nt)
                acc[mt][nt] = __builtin_amdgcn_mfma_f32_16x16x32_bf16(
                    a_cur[mt], bfr[nt], acc[mt][nt], 0, 0, 0);
        #pragma unroll
        for (int mt = 0; mt < 4; ++mt) a_cur[mt] = a_nxt[mt];
    }

    // ---- epilogue: threshold + boundary copy + store ----
    const int mbase = wave * 64;
    const bool boundary = (n0 + BN > k);
    #pragma unroll
    for (int mt = 0; mt < 4; ++mt) {
        #pragma unroll
        for (int nt = 0; nt < 2; ++nt) {
            const int col = n0 + nt * 16 + nlo;
            #pragma unroll
            for (int reg = 0; reg < 4; ++reg) {
                const int row = mbase + mt * 16 + quad * 4 + reg;
                float v = acc[mt][nt][reg];
                v = (fabsf(v) > THR) ? v : 0.f;
                if (boundary && col >= k) v = X[(size_t)row * NC + col];
                outX[(size_t)row * NC + col] = v;
            }
        }
    }
}

extern "C" void kernel_launch(void* const* d_in, const int* in_sizes, int n_in,
                              void* d_out, int out_size, void* d_ws, size_t ws_size,
                              hipStream_t stream)
{
    const float* phi  = (const float*)d_in[0];
    const float* X    = (const float*)d_in[1];
    const float* Y    = (const float*)d_in[2];
    const float* step = (const float*)d_in[3];
    const int*   idx  = (const int*)d_in[4];
    float* out = (float*)d_out;
    unsigned short* A = (unsigned short*)d_ws;   // 256*320*2 = 160 KiB, fragment-linear

    k_copy_phi<<<(M * NR) / 256, 256, 0, stream>>>(phi, out);
    k_prep<<<NR, 256, 0, stream>>>(phi, step, A);
    k_gemm<<<NC / BN, 256, 0, stream>>>(A, X, Y, idx, out + M * NR);
}